// Round 1
// baseline (260.606 us; speedup 1.0000x reference)
//
#include <hip/hip_runtime.h>

#define D_IN  128
#define D_OUT 32
#define H     512
#define W     512
#define W4    128          // W/4 float4 lanes per row
#define HB    16           // output H rows per block
#define ZR    (HB + 8)     // z-conv rows incl. h-halo (24)
#define NTHR  512

// Fused separable 3D conv: z (stride4,pad3) -> h (pad4) -> w (pad4), one block
// per (d, 16-row H tile).
// v2: hbuf eliminated (h+w conv fused via cross-lane shuffles); LDS 80K -> 48K
// so 3 blocks/CU (24 waves) instead of 2 (16 waves). One fewer barrier phase.
__global__ __launch_bounds__(NTHR, 6)   // 6 waves/SIMD -> 3 blocks/CU, VGPR<=84
void conv3d_fused(const float* __restrict__ inp, float* __restrict__ out,
                  const float* __restrict__ bxy_p, const float* __restrict__ bz_p,
                  float* __restrict__ blkMin, float* __restrict__ blkMax) {
    __shared__ float zbuf[ZR * W];   // 48 KiB
    __shared__ float smin[8], smax[8];

    const int d  = blockIdx.x >> 5;        // 32 h-tiles per output slice
    const int h0 = (blockIdx.x & 31) * HB;

    const float bz = bz_p[0], bx = bxy_p[0];
    const float iz = 1.0f / (2.0f * bz * bz);
    const float ix = 1.0f / (2.0f * bx * bx);
    float wz[9], wx[9];
#pragma unroll
    for (int k = 0; k < 9; ++k) {
        float dd = (float)(k - 4);
        wz[k] = expf(-dd * dd * iz);
        wx[k] = expf(-dd * dd * ix);
    }

    const float4* in4 = (const float4*)inp;
    float4* z4 = (float4*)zbuf;

    // ---- Step 1: z-conv (stride 4, pad 3) into zbuf rows [h0-4, h0+20) ----
    for (int t = threadIdx.x; t < ZR * W4; t += NTHR) {
        int r  = t >> 7;            // 0..23 (uniform within a wave)
        int c4 = t & (W4 - 1);
        int h  = h0 - 4 + r;
        float4 acc = make_float4(0.f, 0.f, 0.f, 0.f);
        if ((unsigned)h < H) {
            int base = h * W4 + c4;
#pragma unroll
            for (int k = 0; k < 9; ++k) {
                int din = 4 * d - 3 + k;   // wave-uniform predicate
                if ((unsigned)din < D_IN) {
                    float4 v = in4[din * (H * W4) + base];
                    acc.x += v.x * wz[k]; acc.y += v.y * wz[k];
                    acc.z += v.z * wz[k]; acc.w += v.w * wz[k];
                }
            }
        }
        z4[t] = acc;
    }
    __syncthreads();

    // ---- Step 2: fused h-conv + w-conv, neighbors via shuffles ----
    const int lane = threadIdx.x & 63;
    float lmin =  3.402823466e38f;
    float lmax = -3.402823466e38f;
    float4* out4 = (float4*)out;

    for (int t = threadIdx.x; t < HB * W4; t += NTHR) {
        int r  = t >> 7;            // 0..15 (uniform within a wave)
        int c4 = t & (W4 - 1);      // consecutive across lanes

        // h-conv at (r, c4)
        float4 v = make_float4(0.f, 0.f, 0.f, 0.f);
#pragma unroll
        for (int k = 0; k < 9; ++k) {
            float4 z = z4[(r + k) * W4 + c4];
            v.x += z.x * wx[k]; v.y += z.y * wx[k];
            v.z += z.z * wx[k]; v.w += z.w * wx[k];
        }

        // w-neighbors: lane-1 / lane+1 hold c4-1 / c4+1 (same row)
        float4 va, vc;
        va.x = __shfl_up(v.x, 1, 64);  va.y = __shfl_up(v.y, 1, 64);
        va.z = __shfl_up(v.z, 1, 64);  va.w = __shfl_up(v.w, 1, 64);
        vc.x = __shfl_down(v.x, 1, 64); vc.y = __shfl_down(v.y, 1, 64);
        vc.z = __shfl_down(v.z, 1, 64); vc.w = __shfl_down(v.w, 1, 64);

        // wave-edge lanes recompute their neighbor column from zbuf
        // (2/64 lanes active; OOB column -> zero = w padding)
        if (lane == 0 || lane == 63) {
            int c4n = c4 + ((lane == 0) ? -1 : 1);
            float4 vn = make_float4(0.f, 0.f, 0.f, 0.f);
            if ((unsigned)c4n < W4) {
#pragma unroll
                for (int k = 0; k < 9; ++k) {
                    float4 z = z4[(r + k) * W4 + c4n];
                    vn.x += z.x * wx[k]; vn.y += z.y * wx[k];
                    vn.z += z.z * wx[k]; vn.w += z.w * wx[k];
                }
            }
            if (lane == 0) va = vn; else vc = vn;
        }

        float win[12] = {va.x, va.y, va.z, va.w,
                         v.x,  v.y,  v.z,  v.w,
                         vc.x, vc.y, vc.z, vc.w};
        float4 o = make_float4(0.f, 0.f, 0.f, 0.f);
#pragma unroll
        for (int k = 0; k < 9; ++k) {
            o.x += win[k]     * wx[k];
            o.y += win[k + 1] * wx[k];
            o.z += win[k + 2] * wx[k];
            o.w += win[k + 3] * wx[k];
        }
        out4[(d * H + h0 + r) * W4 + c4] = o;
        lmin = fminf(lmin, fminf(fminf(o.x, o.y), fminf(o.z, o.w)));
        lmax = fmaxf(lmax, fmaxf(fmaxf(o.x, o.y), fmaxf(o.z, o.w)));
    }

    // ---- block min/max reduction (8 waves) ----
#pragma unroll
    for (int off = 32; off > 0; off >>= 1) {
        lmin = fminf(lmin, __shfl_down(lmin, off, 64));
        lmax = fmaxf(lmax, __shfl_down(lmax, off, 64));
    }
    int wv = threadIdx.x >> 6;  // 0..7
    if (lane == 0) { smin[wv] = lmin; smax[wv] = lmax; }
    __syncthreads();
    if (threadIdx.x == 0) {
        float mn = smin[0], mx = smax[0];
#pragma unroll
        for (int i = 1; i < 8; ++i) { mn = fminf(mn, smin[i]); mx = fmaxf(mx, smax[i]); }
        blkMin[blockIdx.x] = mn;
        blkMax[blockIdx.x] = mx;
    }
}

// Reduce per-block min/max (1024 entries) with one block.
__global__ void reduce_kernel(const float* __restrict__ blkMin, const float* __restrict__ blkMax,
                              float* __restrict__ fin, int nblk) {
    float lmin =  3.402823466e38f;
    float lmax = -3.402823466e38f;
    for (int i = threadIdx.x; i < nblk; i += blockDim.x) {
        lmin = fminf(lmin, blkMin[i]);
        lmax = fmaxf(lmax, blkMax[i]);
    }
#pragma unroll
    for (int off = 32; off > 0; off >>= 1) {
        lmin = fminf(lmin, __shfl_down(lmin, off, 64));
        lmax = fmaxf(lmax, __shfl_down(lmax, off, 64));
    }
    __shared__ float smin[4], smax[4];
    int lane = threadIdx.x & 63, wv = threadIdx.x >> 6;
    if (lane == 0) { smin[wv] = lmin; smax[wv] = lmax; }
    __syncthreads();
    if (threadIdx.x == 0) {
        fin[0] = fminf(fminf(smin[0], smin[1]), fminf(smin[2], smin[3]));
        fin[1] = fmaxf(fmaxf(smax[0], smax[1]), fmaxf(smax[2], smax[3]));
    }
}

// Normalize.
__global__ void norm_kernel(const float* __restrict__ in, float* __restrict__ out,
                            const float* __restrict__ fin) {
    int tid = blockIdx.x * blockDim.x + threadIdx.x;
    float mn  = fin[0];
    float inv = 1.0f / (fin[1] - mn);
    float4 v = ((const float4*)in)[tid];
    ((float4*)out)[tid] = make_float4((v.x - mn) * inv, (v.y - mn) * inv,
                                      (v.z - mn) * inv, (v.w - mn) * inv);
}

extern "C" void kernel_launch(void* const* d_in, const int* in_sizes, int n_in,
                              void* d_out, int out_size, void* d_ws, size_t ws_size,
                              hipStream_t stream) {
    const float* inp    = (const float*)d_in[0];
    // mu_z / sig_z only produce a positive global scale, which cancels in the
    // min-max normalization -> unused.
    const float* bet_xy = (const float*)d_in[3];
    const float* bet_z  = (const float*)d_in[4];
    float* out = (float*)d_out;

    char* ws = (char*)d_ws;
    float* fin    = (float*)ws;                  // 2 floats
    float* blkMin = (float*)(ws + 4096);         // 1024 floats
    float* blkMax = (float*)(ws + 8192);         // 1024 floats
    float* bufA   = (float*)(ws + 65536);        // 32 MiB conv output

    const int CONV_GRID = D_OUT * (H / HB);      // 32 * 32 = 1024 blocks
    conv3d_fused<<<CONV_GRID, NTHR, 0, stream>>>(inp, bufA, bet_xy, bet_z, blkMin, blkMax);
    reduce_kernel<<<1, 256, 0, stream>>>(blkMin, blkMax, fin, CONV_GRID);

    const int NTASK = D_OUT * H * W4;            // 2,097,152 float4
    norm_kernel<<<NTASK / 256, 256, 0, stream>>>(bufA, out, fin);
}

// Round 2
// 255.923 us; speedup vs baseline: 1.0183x; 1.0183x over previous
//
#include <hip/hip_runtime.h>

#define D_IN  128
#define D_OUT 32
#define H     512
#define W     512
#define W4    128          // W/4 float4 lanes per row
#define HB    8            // output H rows per block
#define ZR    (HB + 8)     // z-conv rows incl. h-halo (16)
#define NTHR  512
#define CONV_GRID (D_OUT * (H / HB))   // 32 * 64 = 2048 blocks

// Fused separable 3D conv: z (stride4,pad3) -> h (pad4) -> w (pad4), one block
// per (d, 8-row H tile).
// v3: HB 16->8 (zbuf 32 KiB -> 4 blocks/CU = 32 waves, wave-capped); NO
// min-waves launch bound (v2's (512,6) forced VGPR->40 + ~35 MB scratch
// spill traffic); reduce_kernel deleted (norm blocks reduce blkMin/Max
// themselves -> one fewer serialized launch).
__global__ __launch_bounds__(NTHR)
void conv3d_fused(const float* __restrict__ inp, float* __restrict__ out,
                  const float* __restrict__ bxy_p, const float* __restrict__ bz_p,
                  float* __restrict__ blkMin, float* __restrict__ blkMax) {
    __shared__ float zbuf[ZR * W];   // 32 KiB
    __shared__ float smin[8], smax[8];

    const int d  = blockIdx.x >> 6;        // 64 h-tiles per output slice
    const int h0 = (blockIdx.x & 63) * HB;

    const float bz = bz_p[0], bx = bxy_p[0];
    const float iz = 1.0f / (2.0f * bz * bz);
    const float ix = 1.0f / (2.0f * bx * bx);
    float wz[9], wx[9];
#pragma unroll
    for (int k = 0; k < 9; ++k) {
        float dd = (float)(k - 4);
        wz[k] = expf(-dd * dd * iz);
        wx[k] = expf(-dd * dd * ix);
    }

    const float4* in4 = (const float4*)inp;
    float4* z4 = (float4*)zbuf;

    // ---- Step 1: z-conv (stride 4, pad 3) into zbuf rows [h0-4, h0+12) ----
    for (int t = threadIdx.x; t < ZR * W4; t += NTHR) {   // 4 iterations
        int r  = t >> 7;            // 0..15 (uniform within a wave)
        int c4 = t & (W4 - 1);
        int h  = h0 - 4 + r;
        float4 acc = make_float4(0.f, 0.f, 0.f, 0.f);
        if ((unsigned)h < H) {
            int base = h * W4 + c4;
#pragma unroll
            for (int k = 0; k < 9; ++k) {
                int din = 4 * d - 3 + k;   // wave-uniform predicate
                if ((unsigned)din < D_IN) {
                    float4 v = in4[din * (H * W4) + base];
                    acc.x += v.x * wz[k]; acc.y += v.y * wz[k];
                    acc.z += v.z * wz[k]; acc.w += v.w * wz[k];
                }
            }
        }
        z4[t] = acc;
    }
    __syncthreads();

    // ---- Step 2: fused h-conv + w-conv, neighbors via shuffles ----
    const int lane = threadIdx.x & 63;
    float lmin =  3.402823466e38f;
    float lmax = -3.402823466e38f;
    float4* out4 = (float4*)out;

    for (int t = threadIdx.x; t < HB * W4; t += NTHR) {   // 2 iterations
        int r  = t >> 7;            // 0..7 (uniform within a wave)
        int c4 = t & (W4 - 1);      // consecutive across lanes

        // h-conv at (r, c4)
        float4 v = make_float4(0.f, 0.f, 0.f, 0.f);
#pragma unroll
        for (int k = 0; k < 9; ++k) {
            float4 z = z4[(r + k) * W4 + c4];
            v.x += z.x * wx[k]; v.y += z.y * wx[k];
            v.z += z.z * wx[k]; v.w += z.w * wx[k];
        }

        // w-neighbors: lane-1 / lane+1 hold c4-1 / c4+1 (same row)
        float4 va, vc;
        va.x = __shfl_up(v.x, 1, 64);  va.y = __shfl_up(v.y, 1, 64);
        va.z = __shfl_up(v.z, 1, 64);  va.w = __shfl_up(v.w, 1, 64);
        vc.x = __shfl_down(v.x, 1, 64); vc.y = __shfl_down(v.y, 1, 64);
        vc.z = __shfl_down(v.z, 1, 64); vc.w = __shfl_down(v.w, 1, 64);

        // wave-edge lanes recompute their neighbor column from zbuf
        // (2/64 lanes active; OOB column -> zero = w padding)
        if (lane == 0 || lane == 63) {
            int c4n = c4 + ((lane == 0) ? -1 : 1);
            float4 vn = make_float4(0.f, 0.f, 0.f, 0.f);
            if ((unsigned)c4n < W4) {
#pragma unroll
                for (int k = 0; k < 9; ++k) {
                    float4 z = z4[(r + k) * W4 + c4n];
                    vn.x += z.x * wx[k]; vn.y += z.y * wx[k];
                    vn.z += z.z * wx[k]; vn.w += z.w * wx[k];
                }
            }
            if (lane == 0) va = vn; else vc = vn;
        }

        float win[12] = {va.x, va.y, va.z, va.w,
                         v.x,  v.y,  v.z,  v.w,
                         vc.x, vc.y, vc.z, vc.w};
        float4 o = make_float4(0.f, 0.f, 0.f, 0.f);
#pragma unroll
        for (int k = 0; k < 9; ++k) {
            o.x += win[k]     * wx[k];
            o.y += win[k + 1] * wx[k];
            o.z += win[k + 2] * wx[k];
            o.w += win[k + 3] * wx[k];
        }
        out4[(d * H + h0 + r) * W4 + c4] = o;
        lmin = fminf(lmin, fminf(fminf(o.x, o.y), fminf(o.z, o.w)));
        lmax = fmaxf(lmax, fmaxf(fmaxf(o.x, o.y), fmaxf(o.z, o.w)));
    }

    // ---- block min/max reduction (8 waves) ----
#pragma unroll
    for (int off = 32; off > 0; off >>= 1) {
        lmin = fminf(lmin, __shfl_down(lmin, off, 64));
        lmax = fmaxf(lmax, __shfl_down(lmax, off, 64));
    }
    int wv = threadIdx.x >> 6;  // 0..7
    if (lane == 0) { smin[wv] = lmin; smax[wv] = lmax; }
    __syncthreads();
    if (threadIdx.x == 0) {
        float mn = smin[0], mx = smax[0];
#pragma unroll
        for (int i = 1; i < 8; ++i) { mn = fminf(mn, smin[i]); mx = fmaxf(mx, smax[i]); }
        blkMin[blockIdx.x] = mn;
        blkMax[blockIdx.x] = mx;
    }
}

// Normalize; each block first reduces the per-block min/max arrays itself
// (8 KB, L2-hot, fully parallel) -> no serialized single-block reduce kernel.
#define NORM_NTHR  256
#define NORM_F4_PER_THR 4
#define NORM_GRID  ((D_OUT * H * W4) / (NORM_NTHR * NORM_F4_PER_THR))  // 2048

__global__ __launch_bounds__(NORM_NTHR)
void norm_kernel(const float* __restrict__ in, float* __restrict__ out,
                 const float* __restrict__ blkMin, const float* __restrict__ blkMax) {
    float lmin =  3.402823466e38f;
    float lmax = -3.402823466e38f;
    for (int i = threadIdx.x; i < CONV_GRID; i += NORM_NTHR) {   // 8 iterations
        lmin = fminf(lmin, blkMin[i]);
        lmax = fmaxf(lmax, blkMax[i]);
    }
#pragma unroll
    for (int off = 32; off > 0; off >>= 1) {
        lmin = fminf(lmin, __shfl_down(lmin, off, 64));
        lmax = fmaxf(lmax, __shfl_down(lmax, off, 64));
    }
    __shared__ float smin[4], smax[4];
    int lane = threadIdx.x & 63, wv = threadIdx.x >> 6;
    if (lane == 0) { smin[wv] = lmin; smax[wv] = lmax; }
    __syncthreads();
    float mn  = fminf(fminf(smin[0], smin[1]), fminf(smin[2], smin[3]));
    float mx  = fmaxf(fmaxf(smax[0], smax[1]), fmaxf(smax[2], smax[3]));
    float inv = 1.0f / (mx - mn);

    const float4* in4  = (const float4*)in;
    float4*       out4 = (float4*)out;
    int base = blockIdx.x * (NORM_NTHR * NORM_F4_PER_THR) + threadIdx.x;
#pragma unroll
    for (int j = 0; j < NORM_F4_PER_THR; ++j) {
        int idx = base + j * NORM_NTHR;
        float4 v = in4[idx];
        out4[idx] = make_float4((v.x - mn) * inv, (v.y - mn) * inv,
                                (v.z - mn) * inv, (v.w - mn) * inv);
    }
}

extern "C" void kernel_launch(void* const* d_in, const int* in_sizes, int n_in,
                              void* d_out, int out_size, void* d_ws, size_t ws_size,
                              hipStream_t stream) {
    const float* inp    = (const float*)d_in[0];
    // mu_z / sig_z only produce a positive global scale, which cancels in the
    // min-max normalization -> unused.
    const float* bet_xy = (const float*)d_in[3];
    const float* bet_z  = (const float*)d_in[4];
    float* out = (float*)d_out;

    char* ws = (char*)d_ws;
    float* blkMin = (float*)(ws + 4096);         // 2048 floats
    float* blkMax = (float*)(ws + 16384);        // 2048 floats
    float* bufA   = (float*)(ws + 65536);        // 32 MiB conv output

    conv3d_fused<<<CONV_GRID, NTHR, 0, stream>>>(inp, bufA, bet_xy, bet_z, blkMin, blkMax);
    norm_kernel<<<NORM_GRID, NORM_NTHR, 0, stream>>>(bufA, out, blkMin, blkMax);
}

// Round 3
// 233.740 us; speedup vs baseline: 1.1149x; 1.0949x over previous
//
#include <hip/hip_runtime.h>

#define D_IN  128
#define D_OUT 32
#define H     512
#define W     512
#define W4    128          // W/4 float4 lanes per row
#define HB    16           // output H rows per block
#define ZR    (HB + 8)     // z-conv rows incl. h-halo (24)
#define NTHR  512
#define CONV_GRID (D_OUT * (H / HB))   // 32 * 32 = 1024 blocks

// Fused separable 3D conv: z (stride4,pad3) -> h (pad4) -> w (pad4).
// v4: step-1 taps loaded 9-deep into explicit registers (vv[9] + sched_barrier)
// to fix the ~2-loads-in-flight latency serialization seen at VGPR=44
// (1.8 TB/s = Little's law for ~2.6KB/CU outstanding). Interior-d fast path
// drops per-tap predicates. HB back to 16 (halo 1.5x, zbuf 48K -> 3 blk/CU).
__global__ __launch_bounds__(NTHR)
void conv3d_fused(const float* __restrict__ inp, float* __restrict__ out,
                  const float* __restrict__ bxy_p, const float* __restrict__ bz_p,
                  float* __restrict__ blkMin, float* __restrict__ blkMax) {
    __shared__ float zbuf[ZR * W];   // 48 KiB
    __shared__ float smin[8], smax[8];

    const int d  = blockIdx.x >> 5;        // 32 h-tiles per output slice
    const int h0 = (blockIdx.x & 31) * HB;

    const float bz = bz_p[0], bx = bxy_p[0];
    const float iz = 1.0f / (2.0f * bz * bz);
    const float ix = 1.0f / (2.0f * bx * bx);
    float wz[9], wx[9];
#pragma unroll
    for (int k = 0; k < 9; ++k) {
        float dd = (float)(k - 4);
        wz[k] = expf(-dd * dd * iz);
        wx[k] = expf(-dd * dd * ix);
    }

    const float4* in4 = (const float4*)inp;
    float4* z4 = (float4*)zbuf;

    const int dinBase = 4 * d - 3;
    const bool interior = (d >= 1) && (d <= 30);   // all 9 taps in-range

    // ---- Step 1: z-conv (stride 4, pad 3) into zbuf rows [h0-4, h0+20) ----
    for (int t = threadIdx.x; t < ZR * W4; t += NTHR) {   // 6 iterations
        int r  = t >> 7;            // 0..23 (uniform within a wave)
        int c4 = t & (W4 - 1);
        int h  = h0 - 4 + r;
        float4 acc = make_float4(0.f, 0.f, 0.f, 0.f);
        if ((unsigned)h < H) {
            const float4* p = in4 + (ptrdiff_t)dinBase * (H * W4) + h * W4 + c4;
            if (interior) {
                float4 vv[9];
#pragma unroll
                for (int k = 0; k < 9; ++k) vv[k] = p[k * (H * W4)];
                __builtin_amdgcn_sched_barrier(0);   // all 9 loads in flight
#pragma unroll
                for (int k = 0; k < 9; ++k) {
                    acc.x += vv[k].x * wz[k]; acc.y += vv[k].y * wz[k];
                    acc.z += vv[k].z * wz[k]; acc.w += vv[k].w * wz[k];
                }
            } else {
#pragma unroll
                for (int k = 0; k < 9; ++k) {
                    int din = dinBase + k;   // wave-uniform predicate
                    if ((unsigned)din < D_IN) {
                        float4 v = p[k * (H * W4)];
                        acc.x += v.x * wz[k]; acc.y += v.y * wz[k];
                        acc.z += v.z * wz[k]; acc.w += v.w * wz[k];
                    }
                }
            }
        }
        z4[t] = acc;
    }
    __syncthreads();

    // ---- Step 2: fused h-conv + w-conv, neighbors via shuffles ----
    const int lane = threadIdx.x & 63;
    float lmin =  3.402823466e38f;
    float lmax = -3.402823466e38f;
    float4* out4 = (float4*)out;

    for (int t = threadIdx.x; t < HB * W4; t += NTHR) {   // 4 iterations
        int r  = t >> 7;            // 0..15 (uniform within a wave)
        int c4 = t & (W4 - 1);      // consecutive across lanes

        // h-conv at (r, c4)
        float4 v = make_float4(0.f, 0.f, 0.f, 0.f);
#pragma unroll
        for (int k = 0; k < 9; ++k) {
            float4 z = z4[(r + k) * W4 + c4];
            v.x += z.x * wx[k]; v.y += z.y * wx[k];
            v.z += z.z * wx[k]; v.w += z.w * wx[k];
        }

        // w-neighbors: lane-1 / lane+1 hold c4-1 / c4+1 (same row)
        float4 va, vc;
        va.x = __shfl_up(v.x, 1, 64);  va.y = __shfl_up(v.y, 1, 64);
        va.z = __shfl_up(v.z, 1, 64);  va.w = __shfl_up(v.w, 1, 64);
        vc.x = __shfl_down(v.x, 1, 64); vc.y = __shfl_down(v.y, 1, 64);
        vc.z = __shfl_down(v.z, 1, 64); vc.w = __shfl_down(v.w, 1, 64);

        // wave-edge lanes recompute their neighbor column from zbuf
        // (2/64 lanes active; OOB column -> zero = w padding)
        if (lane == 0 || lane == 63) {
            int c4n = c4 + ((lane == 0) ? -1 : 1);
            float4 vn = make_float4(0.f, 0.f, 0.f, 0.f);
            if ((unsigned)c4n < W4) {
#pragma unroll
                for (int k = 0; k < 9; ++k) {
                    float4 z = z4[(r + k) * W4 + c4n];
                    vn.x += z.x * wx[k]; vn.y += z.y * wx[k];
                    vn.z += z.z * wx[k]; vn.w += z.w * wx[k];
                }
            }
            if (lane == 0) va = vn; else vc = vn;
        }

        float win[12] = {va.x, va.y, va.z, va.w,
                         v.x,  v.y,  v.z,  v.w,
                         vc.x, vc.y, vc.z, vc.w};
        float4 o = make_float4(0.f, 0.f, 0.f, 0.f);
#pragma unroll
        for (int k = 0; k < 9; ++k) {
            o.x += win[k]     * wx[k];
            o.y += win[k + 1] * wx[k];
            o.z += win[k + 2] * wx[k];
            o.w += win[k + 3] * wx[k];
        }
        out4[(d * H + h0 + r) * W4 + c4] = o;
        lmin = fminf(lmin, fminf(fminf(o.x, o.y), fminf(o.z, o.w)));
        lmax = fmaxf(lmax, fmaxf(fmaxf(o.x, o.y), fmaxf(o.z, o.w)));
    }

    // ---- block min/max reduction (8 waves) ----
#pragma unroll
    for (int off = 32; off > 0; off >>= 1) {
        lmin = fminf(lmin, __shfl_down(lmin, off, 64));
        lmax = fmaxf(lmax, __shfl_down(lmax, off, 64));
    }
    int wv = threadIdx.x >> 6;  // 0..7
    if (lane == 0) { smin[wv] = lmin; smax[wv] = lmax; }
    __syncthreads();
    if (threadIdx.x == 0) {
        float mn = smin[0], mx = smax[0];
#pragma unroll
        for (int i = 1; i < 8; ++i) { mn = fminf(mn, smin[i]); mx = fmaxf(mx, smax[i]); }
        blkMin[blockIdx.x] = mn;
        blkMax[blockIdx.x] = mx;
    }
}

// Normalize; each block first reduces the per-block min/max arrays itself
// (4 KB, L2-hot, fully parallel) -> no serialized single-block reduce kernel.
#define NORM_NTHR  256
#define NORM_F4_PER_THR 4
#define NORM_GRID  ((D_OUT * H * W4) / (NORM_NTHR * NORM_F4_PER_THR))  // 2048

__global__ __launch_bounds__(NORM_NTHR)
void norm_kernel(const float* __restrict__ in, float* __restrict__ out,
                 const float* __restrict__ blkMin, const float* __restrict__ blkMax) {
    float lmin =  3.402823466e38f;
    float lmax = -3.402823466e38f;
    for (int i = threadIdx.x; i < CONV_GRID; i += NORM_NTHR) {   // 4 iterations
        lmin = fminf(lmin, blkMin[i]);
        lmax = fmaxf(lmax, blkMax[i]);
    }
#pragma unroll
    for (int off = 32; off > 0; off >>= 1) {
        lmin = fminf(lmin, __shfl_down(lmin, off, 64));
        lmax = fmaxf(lmax, __shfl_down(lmax, off, 64));
    }
    __shared__ float smin[4], smax[4];
    int lane = threadIdx.x & 63, wv = threadIdx.x >> 6;
    if (lane == 0) { smin[wv] = lmin; smax[wv] = lmax; }
    __syncthreads();
    float mn  = fminf(fminf(smin[0], smin[1]), fminf(smin[2], smin[3]));
    float mx  = fmaxf(fmaxf(smax[0], smax[1]), fmaxf(smax[2], smax[3]));
    float inv = 1.0f / (mx - mn);

    const float4* in4  = (const float4*)in;
    float4*       out4 = (float4*)out;
    int base = blockIdx.x * (NORM_NTHR * NORM_F4_PER_THR) + threadIdx.x;
#pragma unroll
    for (int j = 0; j < NORM_F4_PER_THR; ++j) {
        int idx = base + j * NORM_NTHR;
        float4 v = in4[idx];
        out4[idx] = make_float4((v.x - mn) * inv, (v.y - mn) * inv,
                                (v.z - mn) * inv, (v.w - mn) * inv);
    }
}

extern "C" void kernel_launch(void* const* d_in, const int* in_sizes, int n_in,
                              void* d_out, int out_size, void* d_ws, size_t ws_size,
                              hipStream_t stream) {
    const float* inp    = (const float*)d_in[0];
    // mu_z / sig_z only produce a positive global scale, which cancels in the
    // min-max normalization -> unused.
    const float* bet_xy = (const float*)d_in[3];
    const float* bet_z  = (const float*)d_in[4];
    float* out = (float*)d_out;

    char* ws = (char*)d_ws;
    float* blkMin = (float*)(ws + 4096);         // 1024 floats
    float* blkMax = (float*)(ws + 16384);        // 1024 floats
    float* bufA   = (float*)(ws + 65536);        // 32 MiB conv output

    conv3d_fused<<<CONV_GRID, NTHR, 0, stream>>>(inp, bufA, bet_xy, bet_z, blkMin, blkMax);
    norm_kernel<<<NORM_GRID, NORM_NTHR, 0, stream>>>(bufA, out, blkMin, blkMax);
}